// Round 10
// baseline (545.459 us; speedup 1.0000x reference)
//
#include <hip/hip_runtime.h>
#include <hip/hip_bf16.h>
#include <stdint.h>

#define NNODES 50000
#define NEDGES 800000
#define HC 256

typedef unsigned short u16;
typedef __attribute__((ext_vector_type(8))) short bf16x8;
typedef __attribute__((ext_vector_type(4))) float f32x4;

__device__ __forceinline__ float b2f(u16 v) {
    return __uint_as_float(((unsigned)v) << 16);
}
__device__ __forceinline__ u16 f2b(float f) {
    unsigned u = __float_as_uint(f);
    u += 0x7fff + ((u >> 16) & 1);
    return (u16)(u >> 16);
}
__device__ __forceinline__ float rdp(const void* p, long i, int bf) {
    return bf ? b2f(((const u16*)p)[i]) : ((const float*)p)[i];
}

// param table: W1,atts1,attd1,We1,atte1,b1,g1,be1,W2,atts2,attd2,We2,atte2,b2,g2,be2,Wout,bout
__device__ __constant__ int dPO[19] = {0,16384,16640,16896,20992,21248,21504,21760,22016,
                                       87552,87808,88064,92160,92416,92672,92928,93184,93440,93441};
static const int hPO[19] = {0,16384,16640,16896,20992,21248,21504,21760,22016,
                            87552,87808,88064,92160,92416,92672,92928,93184,93440,93441};
#define TOTP 93441

// ---------------- prep0: zero workspace zone + dtype detect, one dispatch ----------------
__global__ __launch_bounds__(256) void prep0(unsigned* __restrict__ zp, long nwords,
                                             const unsigned* __restrict__ xbits,
                                             int* __restrict__ flag) {
    if (blockIdx.x < 128) {
        long i = (long)blockIdx.x * 256 + threadIdx.x;
        long stride = 128L * 256;
        for (; i < nwords; i += stride) zp[i] = 0u;
    } else {
        __shared__ int cnt;
        if (threadIdx.x == 0) cnt = 0;
        __syncthreads();
        int sane = 0;
        for (int i = threadIdx.x; i < 1024; i += 256) {
            unsigned lo = xbits[i] & 0xffffu;
            int e = (int)((lo >> 7) & 0xff);
            if (e >= 117 && e <= 133) sane++;
        }
        atomicAdd(&cnt, sane);
        __syncthreads();
        if (threadIdx.x == 0) *flag = (cnt >= 512) ? 1 : 0;
    }
}

// ---------------- param_prep: all input conversion + weight prep + edge_deg ----------------
struct Ptrs18 { const void* s[18]; };

#define NB_XB 512
#define NB_WT1 64
#define NB_WT2 256
#define NB_PALL ((TOTP + 255) / 256)
#define NB_DEG ((NEDGES + 255) / 256)
#define JB1 (NB_XB)
#define JB2 (JB1 + NB_WT1)
#define JB3 (JB2 + NB_WT2)
#define JB4 (JB3 + NB_PALL)
#define JB5 (JB4 + 1)
#define JB6 (JB5 + 1)
#define JB7 (JB6 + 4)
#define NB_PREP (JB7 + NB_DEG)

__global__ __launch_bounds__(256) void param_prep(
    Ptrs18 pp, const void* __restrict__ x_raw, const int* __restrict__ edst,
    const int* __restrict__ flag,
    u16* __restrict__ xb, u16* __restrict__ pall,
    u16* __restrict__ WT1, u16* __restrict__ WT2,
    float* __restrict__ ve1, float* __restrict__ ve2,
    float* __restrict__ us1, float* __restrict__ ud1,
    float* __restrict__ us2, float* __restrict__ ud2,
    int* __restrict__ deg) {
    int b = blockIdx.x, t = threadIdx.x;
    if (b >= JB7) {  // edge_deg histogram
        int e = (b - JB7) * 256 + t;
        if (e < NEDGES) atomicAdd(&deg[edst[e]], 1);
        return;
    }
    int bf = *flag;
    if (b < JB1) {  // x -> xb (octet-vectorized)
        long no = (long)NNODES * 64 / 8;
        long i = (long)b * 256 + t;
        long stride = (long)NB_XB * 256;
        if (bf) {
            const uint4* s = (const uint4*)x_raw;
            uint4* d = (uint4*)xb;
            for (; i < no; i += stride) d[i] = s[i];
        } else {
            const float4* s = (const float4*)x_raw;
            uint4* d = (uint4*)xb;
            for (; i < no; i += stride) {
                float4 a = s[i * 2], c = s[i * 2 + 1];
                uint4 o;
                o.x = (unsigned)f2b(a.x) | ((unsigned)f2b(a.y) << 16);
                o.y = (unsigned)f2b(a.z) | ((unsigned)f2b(a.w) << 16);
                o.z = (unsigned)f2b(c.x) | ((unsigned)f2b(c.y) << 16);
                o.w = (unsigned)f2b(c.z) | ((unsigned)f2b(c.w) << 16);
                d[i] = o;
            }
        }
        return;
    }
    if (b < JB2) {  // WT1: W1[64][256] -> [256][64]
        int i = (b - JB1) * 256 + t;
        int k = i >> 8, c = i & 255;
        WT1[c * 64 + k] = bf ? ((const u16*)pp.s[0])[i] : f2b(((const float*)pp.s[0])[i]);
        return;
    }
    if (b < JB3) {  // WT2: W2[256][256] -> [256][256]
        int i = (b - JB2) * 256 + t;
        int k = i >> 8, c = i & 255;
        WT2[c * 256 + k] = bf ? ((const u16*)pp.s[8])[i] : f2b(((const float*)pp.s[8])[i]);
        return;
    }
    if (b < JB4) {  // pall conversion (bias/g/be/Wout/bout consumers)
        int i = (b - JB3) * 256 + t;
        if (i >= TOTP) return;
        int idx = 0;
        #pragma unroll
        for (int j = 1; j < 18; j++) idx += (i >= dPO[j]) ? 1 : 0;
        int rel = i - dPO[idx];
        pall[i] = bf ? ((const u16*)pp.s[idx])[rel] : f2b(((const float*)pp.s[idx])[rel]);
        return;
    }
    if (b < JB5) {  // ve1 / ve2 from raw We, atte
        if (t < 128) {
            int i = t & 63;
            int f = i >> 2, h = i & 3;
            const void* W = (t < 64) ? pp.s[3] : pp.s[11];
            const void* A = (t < 64) ? pp.s[4] : pp.s[12];
            float* o = (t < 64) ? ve1 : ve2;
            float s = 0.f;
            for (int c = 0; c < 64; c++)
                s += rdp(W, f * 256 + h * 64 + c, bf) * rdp(A, h * 64 + c, bf);
            o[i] = s;
        }
        return;
    }
    if (b < JB6) {  // us1/ud1 from raw W1, atts1, attd1 (256 entries)
        int f = t >> 2, h = t & 3;
        float sa = 0.f, sb = 0.f;
        for (int c = 0; c < 64; c++) {
            float w = rdp(pp.s[0], f * 256 + h * 64 + c, bf);
            sa += w * rdp(pp.s[1], h * 64 + c, bf);
            sb += w * rdp(pp.s[2], h * 64 + c, bf);
        }
        us1[t] = sa;
        ud1[t] = sb;
        return;
    }
    {  // us2/ud2 from raw W2, atts2, attd2 (1024 entries, exactly 4 blocks)
        int i = (b - JB6) * 256 + t;
        if (i >= 1024) return;
        int f = i >> 2, h = i & 3;
        float sa = 0.f, sb = 0.f;
        for (int c = 0; c < 64; c++) {
            float w = rdp(pp.s[8], f * 256 + h * 64 + c, bf);
            sa += w * rdp(pp.s[9], h * 64 + c, bf);
            sb += w * rdp(pp.s[10], h * 64 + c, bf);
        }
        us2[i] = sa;
        ud2[i] = sb;
    }
}

// ---------------- CSR: per-256-block sums ----------------
__global__ void block_sum(const int* __restrict__ deg, int* __restrict__ bsums, int n) {
    __shared__ int lds[256];
    int i = blockIdx.x * 256 + threadIdx.x;
    lds[threadIdx.x] = (i < n) ? deg[i] : 0;
    __syncthreads();
    for (int s = 128; s; s >>= 1) {
        if (threadIdx.x < s) lds[threadIdx.x] += lds[threadIdx.x + s];
        __syncthreads();
    }
    if (threadIdx.x == 0) bsums[blockIdx.x] = lds[0];
}

// ---------------- CSR: fused block-prefix scan + offset write ----------------
__global__ void scan_write(const int* __restrict__ bsums, const int* __restrict__ deg,
                           int* __restrict__ off, int* __restrict__ cursor, int n, int nb) {
    __shared__ int sb[256];
    __shared__ int lds[256];
    int t = threadIdx.x;
    int v = (t < nb) ? bsums[t] : 0;
    sb[t] = v;
    __syncthreads();
    for (int s = 1; s < 256; s <<= 1) {
        int u = (t >= s) ? sb[t - s] : 0;
        __syncthreads();
        sb[t] += u;
        __syncthreads();
    }
    int boff = sb[blockIdx.x] - bsums[blockIdx.x];  // exclusive prefix of this block
    int i = blockIdx.x * 256 + t;
    int dv = (i < n) ? deg[i] : 0;
    lds[t] = dv;
    __syncthreads();
    for (int s = 1; s < 256; s <<= 1) {
        int u = (t >= s) ? lds[t - s] : 0;
        __syncthreads();
        lds[t] += u;
        __syncthreads();
    }
    int exc = lds[t] - dv + boff;
    if (i < n) { off[i] = exc; cursor[i] = exc; }
}

// ---------------- edge stage body: one 32B record per edge, scattered once -------------
__device__ __forceinline__ void edge_body(
    const void* __restrict__ eattr_raw, const int* __restrict__ flag,
    const int* __restrict__ esrc, const int* __restrict__ edst,
    const float* __restrict__ ve1, const float* __restrict__ ve2,
    int* __restrict__ cursor, uint4* __restrict__ rec, int eb) {
    int e = eb * 256 + threadIdx.x;
    if (e >= NEDGES) return;
    float a[16];
    if (*flag) {
        const u16* s = (const u16*)eattr_raw + (long)e * 16;
        const uint4* q = (const uint4*)s;
        uint4 q0 = q[0], q1 = q[1];
        unsigned w0[8] = {q0.x, q0.y, q0.z, q0.w, q1.x, q1.y, q1.z, q1.w};
        #pragma unroll
        for (int j = 0; j < 8; j++) {
            a[2 * j] = b2f((u16)(w0[j] & 0xffff));
            a[2 * j + 1] = b2f((u16)(w0[j] >> 16));
        }
    } else {
        const float* s = (const float*)eattr_raw + (long)e * 16;
        #pragma unroll
        for (int j = 0; j < 16; j += 4) {
            float4 q = *(const float4*)(s + j);
            a[j] = q.x; a[j + 1] = q.y; a[j + 2] = q.z; a[j + 3] = q.w;
        }
    }
    float s1[4], s2[4];
    #pragma unroll
    for (int h = 0; h < 4; h++) {
        float t1 = 0.f, t2 = 0.f;
        #pragma unroll
        for (int f = 0; f < 16; f++) {
            t1 += a[f] * ve1[f * 4 + h];
            t2 += a[f] * ve2[f * 4 + h];
        }
        s1[h] = t1;
        s2[h] = t2;
    }
    unsigned a1lo = (unsigned)f2b(s1[0]) | ((unsigned)f2b(s1[1]) << 16);
    unsigned a1hi = (unsigned)f2b(s1[2]) | ((unsigned)f2b(s1[3]) << 16);
    unsigned a2lo = (unsigned)f2b(s2[0]) | ((unsigned)f2b(s2[1]) << 16);
    unsigned a2hi = (unsigned)f2b(s2[2]) | ((unsigned)f2b(s2[3]) << 16);
    int d = edst[e];
    int p = atomicAdd(&cursor[d], 1);
    unsigned src = (unsigned)esrc[e];
    rec[(long)p * 2 + 0] = make_uint4(src, a1lo, a1hi, 0u);
    rec[(long)p * 2 + 1] = make_uint4(src, a2lo, a2hi, 0u);
}

// ---------------- tiled MFMA GEMM body (optional fused BN+ReLU on A fragments) ---------
__device__ __forceinline__ void gload_lds16(const u16* g, u16* l) {
    __builtin_amdgcn_global_load_lds(
        (const __attribute__((address_space(1))) unsigned*)g,
        (__attribute__((address_space(3))) unsigned*)l, 16, 0, 0);
}

template <int K, bool BN>
__device__ __forceinline__ void gemm_body(const u16* __restrict__ A,
                                          const u16* __restrict__ WT,
                                          const float* __restrict__ coef,
                                          u16* __restrict__ out, int bid) {
    __shared__ u16 As[128 * 32];
    __shared__ u16 Bs[128 * 32];
    int tid = threadIdx.x;
    int wave = tid >> 6, lane = tid & 63;
    int wr = wave >> 1, wc = wave & 1;
    int quad = lane >> 4, l15 = lane & 15;
    long row0 = (long)(bid >> 1) * 128;
    int col0 = (bid & 1) * 128;
    int srow = lane >> 2;
    int soct = (lane & 3) * 8;
    f32x4 acc[4][4] = {};
    for (int kk = 0; kk < K; kk += 32) {
        #pragma unroll
        for (int sub = 0; sub < 2; sub++) {
            int rr = wave * 32 + sub * 16;
            long gr = row0 + rr + srow;
            if (gr >= NNODES) gr = NNODES - 1;
            gload_lds16(A + gr * K + kk + soct, &As[rr * 32]);
            gload_lds16(WT + (long)(col0 + rr + srow) * K + kk + soct, &Bs[rr * 32]);
        }
        __syncthreads();
        bf16x8 av[4], bv[4];
        #pragma unroll
        for (int m = 0; m < 4; m++)
            av[m] = *(const bf16x8*)&As[(wr * 64 + m * 16 + l15) * 32 + quad * 8];
        if (BN) {
            int kb = kk + quad * 8;
            float4 sc0 = *(const float4*)(coef + kb);
            float4 sc1 = *(const float4*)(coef + kb + 4);
            float4 sh0 = *(const float4*)(coef + 256 + kb);
            float4 sh1 = *(const float4*)(coef + 256 + kb + 4);
            float scl[8] = {sc0.x, sc0.y, sc0.z, sc0.w, sc1.x, sc1.y, sc1.z, sc1.w};
            float shf[8] = {sh0.x, sh0.y, sh0.z, sh0.w, sh1.x, sh1.y, sh1.z, sh1.w};
            #pragma unroll
            for (int m = 0; m < 4; m++) {
                #pragma unroll
                for (int j = 0; j < 8; j++) {
                    float v = b2f((u16)av[m][j]);
                    v = fmaxf(v * scl[j] + shf[j], 0.f);
                    av[m][j] = (short)f2b(v);
                }
            }
        }
        #pragma unroll
        for (int n = 0; n < 4; n++)
            bv[n] = *(const bf16x8*)&Bs[(wc * 64 + n * 16 + l15) * 32 + quad * 8];
        #pragma unroll
        for (int m = 0; m < 4; m++)
            #pragma unroll
            for (int n = 0; n < 4; n++)
                acc[m][n] = __builtin_amdgcn_mfma_f32_16x16x32_bf16(av[m], bv[n],
                                                                    acc[m][n], 0, 0, 0);
        __syncthreads();
    }
    #pragma unroll
    for (int m = 0; m < 4; m++) {
        #pragma unroll
        for (int j = 0; j < 4; j++) {
            long r = row0 + wr * 64 + m * 16 + quad * 4 + j;
            if (r < NNODES) {
                u16* op = out + r * HC + col0 + wc * 64 + l15;
                #pragma unroll
                for (int n = 0; n < 4; n++) op[n * 16] = f2b(acc[m][n][j]);
            }
        }
    }
}

// ---------------- a_s/a_d projection body, vectorized uint2 loads ----------------
template <int K, bool BN>
__device__ __forceinline__ void proj_body(const u16* __restrict__ X,
                                          const float* __restrict__ coef,
                                          const float* __restrict__ us,
                                          const float* __restrict__ ud,
                                          float* __restrict__ as_, float* __restrict__ ad_,
                                          int pb) {
    int gw = (pb * 256 + (int)threadIdx.x) >> 6;
    int lane = threadIdx.x & 63;
    int node, f0;
    if (K == 64) {
        node = gw * 4 + (lane >> 4);
        f0 = (lane & 15) * 4;
    } else {
        node = gw;
        f0 = lane * 4;
    }
    if (node >= NNODES) return;
    uint2 v = *(const uint2*)(X + (long)node * K + f0);
    float xv[4] = {b2f((u16)(v.x & 0xffffu)), b2f((u16)(v.x >> 16)),
                   b2f((u16)(v.y & 0xffffu)), b2f((u16)(v.y >> 16))};
    float pas[4] = {0.f, 0.f, 0.f, 0.f}, pad[4] = {0.f, 0.f, 0.f, 0.f};
    #pragma unroll
    for (int j = 0; j < 4; j++) {
        int f = f0 + j;
        float x = xv[j];
        if (BN) x = fmaxf(x * coef[f] + coef[256 + f], 0.f);
        #pragma unroll
        for (int h = 0; h < 4; h++) {
            pas[h] += x * us[f * 4 + h];
            pad[h] += x * ud[f * 4 + h];
        }
    }
    const int omax = (K == 64) ? 8 : 32;
    #pragma unroll
    for (int h = 0; h < 4; h++) {
        for (int o = omax; o; o >>= 1) {
            pas[h] += __shfl_xor(pas[h], o);
            pad[h] += __shfl_xor(pad[h], o);
        }
    }
    bool wr = (K == 64) ? ((lane & 15) == 0) : (lane == 0);
    if (wr) {
        #pragma unroll
        for (int h = 0; h < 4; h++) {
            as_[node * 4 + h] = pas[h];
            ad_[node * 4 + h] = pad[h];
        }
    }
}

// ---------------- layer-1 mix: edge_stage (3125) + gemm64 (782) + proj64 (3125) --------
#define GT 782
#define EB 3125
#define PB64 3125

__global__ __launch_bounds__(256) void l1_mix(
    const void* __restrict__ eattr_raw, const int* __restrict__ flag,
    const int* __restrict__ esrc, const int* __restrict__ edst,
    const float* __restrict__ ve1, const float* __restrict__ ve2,
    int* __restrict__ cursor, uint4* __restrict__ rec,
    const u16* __restrict__ xb, const u16* __restrict__ WT1, u16* __restrict__ bufA,
    const float* __restrict__ us1, const float* __restrict__ ud1,
    float* __restrict__ as_, float* __restrict__ ad_) {
    int b = blockIdx.x;
    if (b < EB) {
        edge_body(eattr_raw, flag, esrc, edst, ve1, ve2, cursor, rec, b);
        return;
    }
    b -= EB;
    if (b < GT) {
        gemm_body<64, false>(xb, WT1, nullptr, bufA, b);
        return;
    }
    b -= GT;
    proj_body<64, false>(xb, nullptr, us1, ud1, as_, ad_, b);
}

// ---------------- layer-2 mix: gemm256+BN (782) + proj256+BN (12500) ----------------
__global__ __launch_bounds__(256) void l2_mix(
    const u16* __restrict__ h1, const u16* __restrict__ WT2,
    const float* __restrict__ coef, u16* __restrict__ bufA,
    const float* __restrict__ us2, const float* __restrict__ ud2,
    float* __restrict__ as_, float* __restrict__ ad_) {
    int b = blockIdx.x;
    if (b < GT) {
        gemm_body<256, true>(h1, WT2, coef, bufA, b);
        return;
    }
    b -= GT;
    proj_body<256, true>(h1, coef, us2, ud2, as_, ad_, b);
}

// ---------------- fused GAT attention, one wave per dst node ----------------
__global__ __launch_bounds__(256) void gat_fused(
    const u16* __restrict__ xs, const float* __restrict__ as_, const float* __restrict__ ad_,
    const uint4* __restrict__ rec, int layer,
    const int* __restrict__ off, const int* __restrict__ deg,
    const u16* __restrict__ bias, u16* __restrict__ out) {
    __shared__ int s_lds[4][64];
    __shared__ float w_lds[4][64][4];
    int wid = (blockIdx.x * 256 + threadIdx.x) >> 6;
    if (wid >= NNODES) return;
    int wave = threadIdx.x >> 6;
    int lane = threadIdx.x & 63;
    int d = wid;
    int st = off[d], dg = deg[d];
    int slot = lane >> 2, h = lane & 3;
    float adv = ad_[d * 4 + h];
    float m = -1e30f, s = 0.f, sae = 0.f;
    const uint4* rbase = rec + (long)st * 2 + layer;

    if (dg <= 64) {
        for (int i = slot; i < dg; i += 16) {
            uint4 r4 = rbase[(long)i * 2];
            int src = (int)r4.x;
            unsigned wsel = (h & 2) ? r4.z : r4.y;
            float aev = b2f((u16)((h & 1) ? (wsel >> 16) : (wsel & 0xffffu)));
            float t = as_[src * 4 + h] + adv + aev;
            float lg = (t > 0.f) ? t : 0.2f * t;
            if (h == 0) s_lds[wave][i] = src;
            w_lds[wave][i][h] = lg;
            sae += aev;
            float mn = fmaxf(m, lg);
            s = s * __expf(m - mn) + __expf(lg - mn);
            m = mn;
        }
        #pragma unroll
        for (int o = 4; o < 64; o <<= 1) {
            float mo = __shfl_xor(m, o), so = __shfl_xor(s, o), ao = __shfl_xor(sae, o);
            float mn = fmaxf(m, mo);
            s = s * __expf(m - mn) + so * __expf(mo - mn);
            m = mn;
            sae += ao;
        }
        float invs, wself;
        {
            float asv = as_[d * 4 + h];
            float l0 = asv + adv + sae / fmaxf((float)dg, 1.f);
            l0 = (l0 > 0.f) ? l0 : 0.2f * l0;
            float mn = fmaxf(m, l0);
            s = s * __expf(m - mn) + __expf(l0 - mn);
            m = mn;
            invs = 1.f / s;
            wself = __expf(l0 - mn) * invs;
        }
        for (int i = slot; i < dg; i += 16)
            w_lds[wave][i][h] = __expf(w_lds[wave][i][h] - m) * invs;

        int cg = lane & 31, half = lane >> 5;
        int ch8 = cg * 8;
        int h2 = cg >> 3;
        float ws2 = __shfl(wself, h2);
        const u16* xbase = xs + ch8;
        float a0, a1, a2, a3, a4, a5, a6, a7;
        {
            uint4 v = *(const uint4*)(xbase + (long)d * HC);
            float wsf = half ? 0.f : ws2;
            a0 = wsf * b2f((u16)(v.x & 0xffffu)); a1 = wsf * b2f((u16)(v.x >> 16));
            a2 = wsf * b2f((u16)(v.y & 0xffffu)); a3 = wsf * b2f((u16)(v.y >> 16));
            a4 = wsf * b2f((u16)(v.z & 0xffffu)); a5 = wsf * b2f((u16)(v.z >> 16));
            a6 = wsf * b2f((u16)(v.w & 0xffffu)); a7 = wsf * b2f((u16)(v.w >> 16));
        }
        int i = half;
        // ---- 8-deep software pipeline: 8 gathers in flight per lane ----
        for (; i + 14 < dg; i += 16) {
            float w8[8];
            int s8[8];
            #pragma unroll
            for (int u = 0; u < 8; u++) {
                w8[u] = w_lds[wave][i + 2 * u][h2];
                s8[u] = s_lds[wave][i + 2 * u];
            }
            uint4 v8[8];
            #pragma unroll
            for (int u = 0; u < 8; u++)
                v8[u] = *(const uint4*)(xbase + (long)s8[u] * HC);
            #pragma unroll
            for (int u = 0; u < 8; u++) {
                a0 += w8[u] * b2f((u16)(v8[u].x & 0xffffu));
                a1 += w8[u] * b2f((u16)(v8[u].x >> 16));
                a2 += w8[u] * b2f((u16)(v8[u].y & 0xffffu));
                a3 += w8[u] * b2f((u16)(v8[u].y >> 16));
                a4 += w8[u] * b2f((u16)(v8[u].z & 0xffffu));
                a5 += w8[u] * b2f((u16)(v8[u].z >> 16));
                a6 += w8[u] * b2f((u16)(v8[u].w & 0xffffu));
                a7 += w8[u] * b2f((u16)(v8[u].w >> 16));
            }
        }
        for (; i + 6 < dg; i += 8) {
            float wA = w_lds[wave][i][h2];     int sA = s_lds[wave][i];
            float wB = w_lds[wave][i + 2][h2]; int sB = s_lds[wave][i + 2];
            float wC = w_lds[wave][i + 4][h2]; int sC = s_lds[wave][i + 4];
            float wD = w_lds[wave][i + 6][h2]; int sD = s_lds[wave][i + 6];
            uint4 vA = *(const uint4*)(xbase + (long)sA * HC);
            uint4 vB = *(const uint4*)(xbase + (long)sB * HC);
            uint4 vC = *(const uint4*)(xbase + (long)sC * HC);
            uint4 vD = *(const uint4*)(xbase + (long)sD * HC);
            a0 += wA * b2f((u16)(vA.x & 0xffffu)) + wB * b2f((u16)(vB.x & 0xffffu))
                + wC * b2f((u16)(vC.x & 0xffffu)) + wD * b2f((u16)(vD.x & 0xffffu));
            a1 += wA * b2f((u16)(vA.x >> 16))     + wB * b2f((u16)(vB.x >> 16))
                + wC * b2f((u16)(vC.x >> 16))     + wD * b2f((u16)(vD.x >> 16));
            a2 += wA * b2f((u16)(vA.y & 0xffffu)) + wB * b2f((u16)(vB.y & 0xffffu))
                + wC * b2f((u16)(vC.y & 0xffffu)) + wD * b2f((u16)(vD.y & 0xffffu));
            a3 += wA * b2f((u16)(vA.y >> 16))     + wB * b2f((u16)(vB.y >> 16))
                + wC * b2f((u16)(vC.y >> 16))     + wD * b2f((u16)(vD.y >> 16));
            a4 += wA * b2f((u16)(vA.z & 0xffffu)) + wB * b2f((u16)(vB.z & 0xffffu))
                + wC * b2f((u16)(vC.z & 0xffffu)) + wD * b2f((u16)(vD.z & 0xffffu));
            a5 += wA * b2f((u16)(vA.z >> 16))     + wB * b2f((u16)(vB.z >> 16))
                + wC * b2f((u16)(vC.z >> 16))     + wD * b2f((u16)(vD.z >> 16));
            a6 += wA * b2f((u16)(vA.w & 0xffffu)) + wB * b2f((u16)(vB.w & 0xffffu))
                + wC * b2f((u16)(vC.w & 0xffffu)) + wD * b2f((u16)(vD.w & 0xffffu));
            a7 += wA * b2f((u16)(vA.w >> 16))     + wB * b2f((u16)(vB.w >> 16))
                + wC * b2f((u16)(vC.w >> 16))     + wD * b2f((u16)(vD.w >> 16));
        }
        for (; i < dg; i += 2) {
            float wA = w_lds[wave][i][h2]; int sA = s_lds[wave][i];
            uint4 vA = *(const uint4*)(xbase + (long)sA * HC);
            a0 += wA * b2f((u16)(vA.x & 0xffffu)); a1 += wA * b2f((u16)(vA.x >> 16));
            a2 += wA * b2f((u16)(vA.y & 0xffffu)); a3 += wA * b2f((u16)(vA.y >> 16));
            a4 += wA * b2f((u16)(vA.z & 0xffffu)); a5 += wA * b2f((u16)(vA.z >> 16));
            a6 += wA * b2f((u16)(vA.w & 0xffffu)); a7 += wA * b2f((u16)(vA.w >> 16));
        }
        a0 += __shfl_xor(a0, 32); a1 += __shfl_xor(a1, 32);
        a2 += __shfl_xor(a2, 32); a3 += __shfl_xor(a3, 32);
        a4 += __shfl_xor(a4, 32); a5 += __shfl_xor(a5, 32);
        a6 += __shfl_xor(a6, 32); a7 += __shfl_xor(a7, 32);
        if (half == 0) {
            uint4 bv = *(const uint4*)(bias + ch8);
            a0 += b2f((u16)(bv.x & 0xffffu)); a1 += b2f((u16)(bv.x >> 16));
            a2 += b2f((u16)(bv.y & 0xffffu)); a3 += b2f((u16)(bv.y >> 16));
            a4 += b2f((u16)(bv.z & 0xffffu)); a5 += b2f((u16)(bv.z >> 16));
            a6 += b2f((u16)(bv.w & 0xffffu)); a7 += b2f((u16)(bv.w >> 16));
            uint4 ov;
            ov.x = (unsigned)f2b(a0) | ((unsigned)f2b(a1) << 16);
            ov.y = (unsigned)f2b(a2) | ((unsigned)f2b(a3) << 16);
            ov.z = (unsigned)f2b(a4) | ((unsigned)f2b(a5) << 16);
            ov.w = (unsigned)f2b(a6) | ((unsigned)f2b(a7) << 16);
            *(uint4*)(out + (long)d * HC + ch8) = ov;
        }
        return;
    }

    // ---------- fallback path (deg > 64): exact ----------
    for (int base = 0; base < dg; base += 16) {
        int i = base + slot;
        float lg = -1e30f, aev = 0.f, w = 0.f;
        if (i < dg) {
            uint4 r4 = rbase[(long)i * 2];
            int src = (int)r4.x;
            unsigned wsel = (h & 2) ? r4.z : r4.y;
            aev = b2f((u16)((h & 1) ? (wsel >> 16) : (wsel & 0xffffu)));
            float t = as_[src * 4 + h] + adv + aev;
            lg = (t > 0.f) ? t : 0.2f * t;
        }
        sae += aev;
        float mn = fmaxf(m, lg);
        if (i < dg) w = __expf(lg - mn);
        s = s * __expf(m - mn) + w;
        m = mn;
    }
    #pragma unroll
    for (int o = 4; o < 64; o <<= 1) {
        float mo = __shfl_xor(m, o), so = __shfl_xor(s, o), ao = __shfl_xor(sae, o);
        float mn = fmaxf(m, mo);
        s = s * __expf(m - mn) + so * __expf(mo - mn);
        m = mn;
        sae += ao;
    }
    float invs, wself;
    {
        float asv = as_[d * 4 + h];
        float l0 = asv + adv + sae / fmaxf((float)dg, 1.f);
        l0 = (l0 > 0.f) ? l0 : 0.2f * l0;
        float mn = fmaxf(m, l0);
        s = s * __expf(m - mn) + __expf(l0 - mn);
        m = mn;
        invs = 1.f / s;
        wself = __expf(l0 - mn) * invs;
    }
    int h2 = lane >> 4;
    float m2 = __shfl(m, h2);
    float is2 = __shfl(invs, h2);
    float ws2 = __shfl(wself, h2);
    float adv2 = __shfl(adv, h2);
    int cb = lane * 4;
    float a0, a1, a2, a3;
    {
        uint2 v = *(const uint2*)(xs + (long)d * HC + cb);
        a0 = ws2 * b2f((u16)(v.x & 0xffffu)); a1 = ws2 * b2f((u16)(v.x >> 16));
        a2 = ws2 * b2f((u16)(v.y & 0xffffu)); a3 = ws2 * b2f((u16)(v.y >> 16));
    }
    int slot16 = lane & 15;
    int lhi = lane & 48;
    for (int base = 0; base < dg; base += 16) {
        int cnt = min(16, dg - base);
        float wv = 0.f;
        int srcl = 0;
        if (slot16 < cnt) {
            uint4 r4 = rbase[(long)(base + slot16) * 2];
            srcl = (int)r4.x;
            unsigned wsel = (h2 & 2) ? r4.z : r4.y;
            float aev = b2f((u16)((h2 & 1) ? (wsel >> 16) : (wsel & 0xffffu)));
            float t = as_[srcl * 4 + h2] + adv2 + aev;
            t = (t > 0.f) ? t : 0.2f * t;
            wv = __expf(t - m2) * is2;
        }
        for (int j = 0; j < cnt; j++) {
            float w0 = __shfl(wv, lhi | j);
            int s0 = __shfl(srcl, j);
            uint2 v0 = *(const uint2*)(xs + (long)s0 * HC + cb);
            a0 += w0 * b2f((u16)(v0.x & 0xffffu));
            a1 += w0 * b2f((u16)(v0.x >> 16));
            a2 += w0 * b2f((u16)(v0.y & 0xffffu));
            a3 += w0 * b2f((u16)(v0.y >> 16));
        }
    }
    u16 o0 = f2b(a0 + b2f(bias[cb + 0]));
    u16 o1 = f2b(a1 + b2f(bias[cb + 1]));
    u16 o2 = f2b(a2 + b2f(bias[cb + 2]));
    u16 o3 = f2b(a3 + b2f(bias[cb + 3]));
    uint2 ov;
    ov.x = (unsigned)o0 | ((unsigned)o1 << 16);
    ov.y = (unsigned)o2 | ((unsigned)o3 << 16);
    *(uint2*)(out + (long)d * HC + cb) = ov;
}

// ---------------- BatchNorm stats (4-row ILP, 512 blocks) + last-block coef finalize ----
__global__ __launch_bounds__(256) void bn_stats(const u16* __restrict__ h,
                                                float* __restrict__ stats,
                                                int* __restrict__ cnt,
                                                const u16* __restrict__ g,
                                                const u16* __restrict__ be,
                                                float* __restrict__ coef) {
    __shared__ float lsum[256], lsq[256];
    __shared__ int last;
    int t = threadIdx.x;
    int p = t & 127;   // column pair -> cols 2p, 2p+1
    int ro = t >> 7;   // 0: rows +0..3 of group, 1: rows +4..7
    float s0 = 0.f, q0 = 0.f, s1 = 0.f, q1 = 0.f;
    const u16* hp = h + 2 * p;
    for (long r = (long)blockIdx.x * 8 + ro * 4; r < NNODES; r += (long)gridDim.x * 8) {
        unsigned v0 = *(const unsigned*)(hp + (r + 0) * HC);
        unsigned v1 = *(const unsigned*)(hp + (r + 1) * HC);
        unsigned v2 = *(const unsigned*)(hp + (r + 2) * HC);
        unsigned v3 = *(const unsigned*)(hp + (r + 3) * HC);
        float l0 = b2f((u16)(v0 & 0xffffu)), h0 = b2f((u16)(v0 >> 16));
        float l1 = b2f((u16)(v1 & 0xffffu)), h1 = b2f((u16)(v1 >> 16));
        float l2 = b2f((u16)(v2 & 0xffffu)), h2 = b2f((u16)(v2 >> 16));
        float l3 = b2f((u16)(v3 & 0xffffu)), h3 = b2f((u16)(v3 >> 16));
        s0 += l0 + l1 + l2 + l3;
        q0 += l0 * l0 + l1 * l1 + l2 * l2 + l3 * l3;
        s1 += h0 + h1 + h2 + h3;
        q1 += h0 * h0 + h1 * h1 + h2 * h2 + h3 * h3;
    }
    if (ro == 1) {
        lsum[2 * p] = s0; lsum[2 * p + 1] = s1;
        lsq[2 * p] = q0;  lsq[2 * p + 1] = q1;
    }
    __syncthreads();
    if (ro == 0) {
        atomicAdd(&stats[2 * p],           s0 + lsum[2 * p]);
        atomicAdd(&stats[2 * p + 1],       s1 + lsum[2 * p + 1]);
        atomicAdd(&stats[256 + 2 * p],     q0 + lsq[2 * p]);
        atomicAdd(&stats[256 + 2 * p + 1], q1 + lsq[2 * p + 1]);
    }
    // last-block finalize (replaces bn_coef dispatch)
    __threadfence();
    __syncthreads();
    if (t == 0) {
        int old = atomicAdd(cnt, 1);
        last = (old == (int)gridDim.x - 1);
    }
    __syncthreads();
    if (last) {
        float sum = atomicAdd(&stats[t], 0.f);       // atomic read: L2-coherent
        float sq  = atomicAdd(&stats[256 + t], 0.f);
        float mu = sum * (1.0f / NNODES);
        float var = sq * (1.0f / NNODES) - mu * mu;
        var = fmaxf(var, 0.f);
        float rs = rsqrtf(var + 1e-5f);
        float sc = b2f(g[t]) * rs;
        coef[t] = sc;
        coef[256 + t] = b2f(be[t]) - sc * mu;
    }
}

// ---------------- output head (+fused BN2+ReLU), vectorized ----------------
__global__ __launch_bounds__(256) void out_head(const u16* __restrict__ h,
                                                const float* __restrict__ coef,
                                                const u16* __restrict__ wout,
                                                const u16* __restrict__ bout,
                                                void* __restrict__ y,
                                                const int* __restrict__ flag) {
    int wid = (blockIdx.x * 256 + threadIdx.x) >> 6;
    int lane = threadIdx.x & 63;
    if (wid >= NNODES) return;
    int c0 = lane * 4;
    uint2 v = *(const uint2*)(h + (long)wid * HC + c0);
    uint2 wv = *(const uint2*)(wout + c0);
    float hv[4] = {b2f((u16)(v.x & 0xffffu)), b2f((u16)(v.x >> 16)),
                   b2f((u16)(v.y & 0xffffu)), b2f((u16)(v.y >> 16))};
    float wf[4] = {b2f((u16)(wv.x & 0xffffu)), b2f((u16)(wv.x >> 16)),
                   b2f((u16)(wv.y & 0xffffu)), b2f((u16)(wv.y >> 16))};
    float p = 0.f;
    #pragma unroll
    for (int j = 0; j < 4; j++) {
        float t = fmaxf(hv[j] * coef[c0 + j] + coef[256 + c0 + j], 0.f);
        p += t * wf[j];
    }
    for (int o = 32; o; o >>= 1) p += __shfl_down(p, o);
    if (lane == 0) {
        float t = p + b2f(bout[0]);
        if (*flag) ((u16*)y)[wid] = f2b(t);
        else       ((float*)y)[wid] = t;
    }
}

extern "C" void kernel_launch(void* const* d_in, const int* in_sizes, int n_in,
                              void* d_out, int out_size, void* d_ws, size_t ws_size,
                              hipStream_t stream) {
    (void)in_sizes; (void)n_in; (void)out_size; (void)ws_size;
    const void* x_raw     = d_in[0];
    const int*  esrc      = (const int*)d_in[1];
    const int*  edst      = (const int*)d_in[2];
    const void* eattr_raw = d_in[3];

    char* ws = (char*)d_ws;
    size_t o = 0;
    auto alloc = [&](size_t bytes) -> char* {
        o = (o + 255) & ~(size_t)255;
        char* p = ws + o;
        o += bytes;
        return p;
    };
    int* dflag = (int*)alloc(256);
    u16* xb   = (u16*)alloc((size_t)NNODES * 64 * 2);
    u16* pall = (u16*)alloc((size_t)TOTP * 2);
    u16 *b1b = pall + hPO[5], *g1b = pall + hPO[6], *be1b = pall + hPO[7],
        *b2b = pall + hPO[13], *g2b = pall + hPO[14], *be2b = pall + hPO[15],
        *Woutb = pall + hPO[16], *boutb = pall + hPO[17];
    u16* WT1 = (u16*)alloc(256 * 64 * 2);
    u16* WT2 = (u16*)alloc(256 * 256 * 2);
    float* ve1 = (float*)alloc(64 * 4);
    float* ve2 = (float*)alloc(64 * 4);
    float* us1 = (float*)alloc(256 * 4);
    float* ud1 = (float*)alloc(256 * 4);
    float* us2 = (float*)alloc(1024 * 4);
    float* ud2 = (float*)alloc(1024 * 4);
    float* coef1 = (float*)alloc(512 * 4);
    float* coef2 = (float*)alloc(512 * 4);
    // zero zone: deg + stats + bn counters
    int* deg = (int*)alloc((size_t)NNODES * 4);
    float* stats1 = (float*)alloc(512 * 4);
    float* stats2 = (float*)alloc(512 * 4);
    int* bnc1 = (int*)alloc(256);
    int* bnc2 = (int*)alloc(256);
    size_t zero_end = o;
    size_t zero_begin = (size_t)((char*)deg - ws);
    // rest
    int* off = (int*)alloc((size_t)NNODES * 4);
    int* cursor = (int*)alloc((size_t)NNODES * 4);
    int* bsums = (int*)alloc(256 * 4);
    uint4* rec = (uint4*)alloc((size_t)NEDGES * 32);
    float* as_ = (float*)alloc((size_t)NNODES * 16);
    float* ad_ = (float*)alloc((size_t)NNODES * 16);
    u16* bufA = (u16*)alloc((size_t)NNODES * HC * 2);  // xs1, then xs2
    u16* bufB = (u16*)alloc((size_t)NNODES * HC * 2);  // h1raw, then h2raw

    long zwords = (long)((zero_end - zero_begin) / 4);
    prep0<<<129, 256, 0, stream>>>((unsigned*)(ws + zero_begin), zwords,
                                   (const unsigned*)x_raw, dflag);

    Ptrs18 pp;
    for (int i = 0; i < 18; i++) pp.s[i] = d_in[4 + i];
    param_prep<<<NB_PREP, 256, 0, stream>>>(pp, x_raw, edst, dflag, xb, pall, WT1, WT2,
                                            ve1, ve2, us1, ud1, us2, ud2, deg);

    int nb = (NNODES + 255) / 256;  // 196
    block_sum<<<nb, 256, 0, stream>>>(deg, bsums, NNODES);
    scan_write<<<nb, 256, 0, stream>>>(bsums, deg, off, cursor, NNODES, nb);

    int wblocks = (NNODES * 64 + 255) / 256;  // 12500 (1 wave per node)

    // layer 1: edge_stage + gemm64 + proj64 in one MPMD dispatch
    l1_mix<<<EB + GT + PB64, 256, 0, stream>>>(eattr_raw, dflag, esrc, edst, ve1, ve2,
                                               cursor, rec, xb, WT1, bufA,
                                               us1, ud1, as_, ad_);
    gat_fused<<<wblocks, 256, 0, stream>>>(bufA, as_, ad_, rec, 0, off, deg, b1b, bufB);
    bn_stats<<<512, 256, 0, stream>>>(bufB, stats1, bnc1, g1b, be1b, coef1);

    // layer 2: gemm256+BN + proj256+BN in one MPMD dispatch
    l2_mix<<<GT + wblocks, 256, 0, stream>>>(bufB, WT2, coef1, bufA, us2, ud2, as_, ad_);
    gat_fused<<<wblocks, 256, 0, stream>>>(bufA, as_, ad_, rec, 1, off, deg, b2b, bufB);
    bn_stats<<<512, 256, 0, stream>>>(bufB, stats2, bnc2, g2b, be2b, coef2);

    // output head (BN2 fused)
    out_head<<<wblocks, 256, 0, stream>>>(bufB, coef2, Woutb, boutb, d_out, dflag);
}

// Round 11
// 530.102 us; speedup vs baseline: 1.0290x; 1.0290x over previous
//
#include <hip/hip_runtime.h>
#include <hip/hip_bf16.h>
#include <stdint.h>

#define NNODES 50000
#define NEDGES 800000
#define HC 256

typedef unsigned short u16;
typedef __attribute__((ext_vector_type(8))) short bf16x8;
typedef __attribute__((ext_vector_type(4))) float f32x4;

__device__ __forceinline__ float b2f(u16 v) {
    return __uint_as_float(((unsigned)v) << 16);
}
__device__ __forceinline__ u16 f2b(float f) {
    unsigned u = __float_as_uint(f);
    u += 0x7fff + ((u >> 16) & 1);
    return (u16)(u >> 16);
}
__device__ __forceinline__ float rdp(const void* p, long i, int bf) {
    return bf ? b2f(((const u16*)p)[i]) : ((const float*)p)[i];
}

// param table: W1,atts1,attd1,We1,atte1,b1,g1,be1,W2,atts2,attd2,We2,atte2,b2,g2,be2,Wout,bout
__device__ __constant__ int dPO[19] = {0,16384,16640,16896,20992,21248,21504,21760,22016,
                                       87552,87808,88064,92160,92416,92672,92928,93184,93440,93441};
static const int hPO[19] = {0,16384,16640,16896,20992,21248,21504,21760,22016,
                            87552,87808,88064,92160,92416,92672,92928,93184,93440,93441};
#define TOTP 93441

// ---------------- prep0: zero workspace zone + dtype detect, one dispatch ----------------
__global__ __launch_bounds__(256) void prep0(unsigned* __restrict__ zp, long nwords,
                                             const unsigned* __restrict__ xbits,
                                             int* __restrict__ flag) {
    if (blockIdx.x < 128) {
        long i = (long)blockIdx.x * 256 + threadIdx.x;
        long stride = 128L * 256;
        for (; i < nwords; i += stride) zp[i] = 0u;
    } else {
        __shared__ int cnt;
        if (threadIdx.x == 0) cnt = 0;
        __syncthreads();
        int sane = 0;
        for (int i = threadIdx.x; i < 1024; i += 256) {
            unsigned lo = xbits[i] & 0xffffu;
            int e = (int)((lo >> 7) & 0xff);
            if (e >= 117 && e <= 133) sane++;
        }
        atomicAdd(&cnt, sane);
        __syncthreads();
        if (threadIdx.x == 0) *flag = (cnt >= 512) ? 1 : 0;
    }
}

// ---------------- param_prep: all input conversion + weight prep + edge_deg ----------------
struct Ptrs18 { const void* s[18]; };

#define NB_XB 512
#define NB_WT1 64
#define NB_WT2 256
#define NB_PALL ((TOTP + 255) / 256)
#define NB_DEG ((NEDGES + 255) / 256)
#define JB1 (NB_XB)
#define JB2 (JB1 + NB_WT1)
#define JB3 (JB2 + NB_WT2)
#define JB4 (JB3 + NB_PALL)
#define JB5 (JB4 + 1)
#define JB6 (JB5 + 1)
#define JB7 (JB6 + 4)
#define NB_PREP (JB7 + NB_DEG)

__global__ __launch_bounds__(256) void param_prep(
    Ptrs18 pp, const void* __restrict__ x_raw, const int* __restrict__ edst,
    const int* __restrict__ flag,
    u16* __restrict__ xb, u16* __restrict__ pall,
    u16* __restrict__ WT1, u16* __restrict__ WT2,
    float* __restrict__ ve1, float* __restrict__ ve2,
    float* __restrict__ us1, float* __restrict__ ud1,
    float* __restrict__ us2, float* __restrict__ ud2,
    int* __restrict__ deg) {
    int b = blockIdx.x, t = threadIdx.x;
    if (b >= JB7) {  // edge_deg histogram
        int e = (b - JB7) * 256 + t;
        if (e < NEDGES) atomicAdd(&deg[edst[e]], 1);
        return;
    }
    int bf = *flag;
    if (b < JB1) {  // x -> xb (octet-vectorized)
        long no = (long)NNODES * 64 / 8;
        long i = (long)b * 256 + t;
        long stride = (long)NB_XB * 256;
        if (bf) {
            const uint4* s = (const uint4*)x_raw;
            uint4* d = (uint4*)xb;
            for (; i < no; i += stride) d[i] = s[i];
        } else {
            const float4* s = (const float4*)x_raw;
            uint4* d = (uint4*)xb;
            for (; i < no; i += stride) {
                float4 a = s[i * 2], c = s[i * 2 + 1];
                uint4 o;
                o.x = (unsigned)f2b(a.x) | ((unsigned)f2b(a.y) << 16);
                o.y = (unsigned)f2b(a.z) | ((unsigned)f2b(a.w) << 16);
                o.z = (unsigned)f2b(c.x) | ((unsigned)f2b(c.y) << 16);
                o.w = (unsigned)f2b(c.z) | ((unsigned)f2b(c.w) << 16);
                d[i] = o;
            }
        }
        return;
    }
    if (b < JB2) {  // WT1: W1[64][256] -> [256][64]
        int i = (b - JB1) * 256 + t;
        int k = i >> 8, c = i & 255;
        WT1[c * 64 + k] = bf ? ((const u16*)pp.s[0])[i] : f2b(((const float*)pp.s[0])[i]);
        return;
    }
    if (b < JB3) {  // WT2: W2[256][256] -> [256][256]
        int i = (b - JB2) * 256 + t;
        int k = i >> 8, c = i & 255;
        WT2[c * 256 + k] = bf ? ((const u16*)pp.s[8])[i] : f2b(((const float*)pp.s[8])[i]);
        return;
    }
    if (b < JB4) {  // pall conversion (bias/g/be/Wout/bout consumers)
        int i = (b - JB3) * 256 + t;
        if (i >= TOTP) return;
        int idx = 0;
        #pragma unroll
        for (int j = 1; j < 18; j++) idx += (i >= dPO[j]) ? 1 : 0;
        int rel = i - dPO[idx];
        pall[i] = bf ? ((const u16*)pp.s[idx])[rel] : f2b(((const float*)pp.s[idx])[rel]);
        return;
    }
    if (b < JB5) {  // ve1 / ve2 from raw We, atte
        if (t < 128) {
            int i = t & 63;
            int f = i >> 2, h = i & 3;
            const void* W = (t < 64) ? pp.s[3] : pp.s[11];
            const void* A = (t < 64) ? pp.s[4] : pp.s[12];
            float* o = (t < 64) ? ve1 : ve2;
            float s = 0.f;
            for (int c = 0; c < 64; c++)
                s += rdp(W, f * 256 + h * 64 + c, bf) * rdp(A, h * 64 + c, bf);
            o[i] = s;
        }
        return;
    }
    if (b < JB6) {  // us1/ud1 from raw W1, atts1, attd1 (256 entries)
        int f = t >> 2, h = t & 3;
        float sa = 0.f, sb = 0.f;
        for (int c = 0; c < 64; c++) {
            float w = rdp(pp.s[0], f * 256 + h * 64 + c, bf);
            sa += w * rdp(pp.s[1], h * 64 + c, bf);
            sb += w * rdp(pp.s[2], h * 64 + c, bf);
        }
        us1[t] = sa;
        ud1[t] = sb;
        return;
    }
    {  // us2/ud2 from raw W2, atts2, attd2 (1024 entries, exactly 4 blocks)
        int i = (b - JB6) * 256 + t;
        if (i >= 1024) return;
        int f = i >> 2, h = i & 3;
        float sa = 0.f, sb = 0.f;
        for (int c = 0; c < 64; c++) {
            float w = rdp(pp.s[8], f * 256 + h * 64 + c, bf);
            sa += w * rdp(pp.s[9], h * 64 + c, bf);
            sb += w * rdp(pp.s[10], h * 64 + c, bf);
        }
        us2[i] = sa;
        ud2[i] = sb;
    }
}

// ---------------- CSR: per-256-block sums ----------------
__global__ void block_sum(const int* __restrict__ deg, int* __restrict__ bsums, int n) {
    __shared__ int lds[256];
    int i = blockIdx.x * 256 + threadIdx.x;
    lds[threadIdx.x] = (i < n) ? deg[i] : 0;
    __syncthreads();
    for (int s = 128; s; s >>= 1) {
        if (threadIdx.x < s) lds[threadIdx.x] += lds[threadIdx.x + s];
        __syncthreads();
    }
    if (threadIdx.x == 0) bsums[blockIdx.x] = lds[0];
}

// ---------------- CSR: fused block-prefix scan + offset write ----------------
__global__ void scan_write(const int* __restrict__ bsums, const int* __restrict__ deg,
                           int* __restrict__ off, int* __restrict__ cursor, int n, int nb) {
    __shared__ int sb[256];
    __shared__ int lds[256];
    int t = threadIdx.x;
    int v = (t < nb) ? bsums[t] : 0;
    sb[t] = v;
    __syncthreads();
    for (int s = 1; s < 256; s <<= 1) {
        int u = (t >= s) ? sb[t - s] : 0;
        __syncthreads();
        sb[t] += u;
        __syncthreads();
    }
    int boff = sb[blockIdx.x] - bsums[blockIdx.x];  // exclusive prefix of this block
    int i = blockIdx.x * 256 + t;
    int dv = (i < n) ? deg[i] : 0;
    lds[t] = dv;
    __syncthreads();
    for (int s = 1; s < 256; s <<= 1) {
        int u = (t >= s) ? lds[t - s] : 0;
        __syncthreads();
        lds[t] += u;
        __syncthreads();
    }
    int exc = lds[t] - dv + boff;
    if (i < n) { off[i] = exc; cursor[i] = exc; }
}

// ---------------- edge stage body: one 32B record per edge, scattered once -------------
__device__ __forceinline__ void edge_body(
    const void* __restrict__ eattr_raw, const int* __restrict__ flag,
    const int* __restrict__ esrc, const int* __restrict__ edst,
    const float* __restrict__ ve1, const float* __restrict__ ve2,
    int* __restrict__ cursor, uint4* __restrict__ rec, int eb) {
    int e = eb * 256 + threadIdx.x;
    if (e >= NEDGES) return;
    float a[16];
    if (*flag) {
        const u16* s = (const u16*)eattr_raw + (long)e * 16;
        const uint4* q = (const uint4*)s;
        uint4 q0 = q[0], q1 = q[1];
        unsigned w0[8] = {q0.x, q0.y, q0.z, q0.w, q1.x, q1.y, q1.z, q1.w};
        #pragma unroll
        for (int j = 0; j < 8; j++) {
            a[2 * j] = b2f((u16)(w0[j] & 0xffff));
            a[2 * j + 1] = b2f((u16)(w0[j] >> 16));
        }
    } else {
        const float* s = (const float*)eattr_raw + (long)e * 16;
        #pragma unroll
        for (int j = 0; j < 16; j += 4) {
            float4 q = *(const float4*)(s + j);
            a[j] = q.x; a[j + 1] = q.y; a[j + 2] = q.z; a[j + 3] = q.w;
        }
    }
    float s1[4], s2[4];
    #pragma unroll
    for (int h = 0; h < 4; h++) {
        float t1 = 0.f, t2 = 0.f;
        #pragma unroll
        for (int f = 0; f < 16; f++) {
            t1 += a[f] * ve1[f * 4 + h];
            t2 += a[f] * ve2[f * 4 + h];
        }
        s1[h] = t1;
        s2[h] = t2;
    }
    unsigned a1lo = (unsigned)f2b(s1[0]) | ((unsigned)f2b(s1[1]) << 16);
    unsigned a1hi = (unsigned)f2b(s1[2]) | ((unsigned)f2b(s1[3]) << 16);
    unsigned a2lo = (unsigned)f2b(s2[0]) | ((unsigned)f2b(s2[1]) << 16);
    unsigned a2hi = (unsigned)f2b(s2[2]) | ((unsigned)f2b(s2[3]) << 16);
    int d = edst[e];
    int p = atomicAdd(&cursor[d], 1);
    unsigned src = (unsigned)esrc[e];
    rec[(long)p * 2 + 0] = make_uint4(src, a1lo, a1hi, 0u);
    rec[(long)p * 2 + 1] = make_uint4(src, a2lo, a2hi, 0u);
}

// ---------------- tiled MFMA GEMM body (optional fused BN+ReLU on A fragments) ---------
__device__ __forceinline__ void gload_lds16(const u16* g, u16* l) {
    __builtin_amdgcn_global_load_lds(
        (const __attribute__((address_space(1))) unsigned*)g,
        (__attribute__((address_space(3))) unsigned*)l, 16, 0, 0);
}

template <int K, bool BN>
__device__ __forceinline__ void gemm_body(const u16* __restrict__ A,
                                          const u16* __restrict__ WT,
                                          const float* __restrict__ coef,
                                          u16* __restrict__ out, int bid) {
    __shared__ u16 As[128 * 32];
    __shared__ u16 Bs[128 * 32];
    int tid = threadIdx.x;
    int wave = tid >> 6, lane = tid & 63;
    int wr = wave >> 1, wc = wave & 1;
    int quad = lane >> 4, l15 = lane & 15;
    long row0 = (long)(bid >> 1) * 128;
    int col0 = (bid & 1) * 128;
    int srow = lane >> 2;
    int soct = (lane & 3) * 8;
    f32x4 acc[4][4] = {};
    for (int kk = 0; kk < K; kk += 32) {
        #pragma unroll
        for (int sub = 0; sub < 2; sub++) {
            int rr = wave * 32 + sub * 16;
            long gr = row0 + rr + srow;
            if (gr >= NNODES) gr = NNODES - 1;
            gload_lds16(A + gr * K + kk + soct, &As[rr * 32]);
            gload_lds16(WT + (long)(col0 + rr + srow) * K + kk + soct, &Bs[rr * 32]);
        }
        __syncthreads();
        bf16x8 av[4], bv[4];
        #pragma unroll
        for (int m = 0; m < 4; m++)
            av[m] = *(const bf16x8*)&As[(wr * 64 + m * 16 + l15) * 32 + quad * 8];
        if (BN) {
            int kb = kk + quad * 8;
            float4 sc0 = *(const float4*)(coef + kb);
            float4 sc1 = *(const float4*)(coef + kb + 4);
            float4 sh0 = *(const float4*)(coef + 256 + kb);
            float4 sh1 = *(const float4*)(coef + 256 + kb + 4);
            float scl[8] = {sc0.x, sc0.y, sc0.z, sc0.w, sc1.x, sc1.y, sc1.z, sc1.w};
            float shf[8] = {sh0.x, sh0.y, sh0.z, sh0.w, sh1.x, sh1.y, sh1.z, sh1.w};
            #pragma unroll
            for (int m = 0; m < 4; m++) {
                #pragma unroll
                for (int j = 0; j < 8; j++) {
                    float v = b2f((u16)av[m][j]);
                    v = fmaxf(v * scl[j] + shf[j], 0.f);
                    av[m][j] = (short)f2b(v);
                }
            }
        }
        #pragma unroll
        for (int n = 0; n < 4; n++)
            bv[n] = *(const bf16x8*)&Bs[(wc * 64 + n * 16 + l15) * 32 + quad * 8];
        #pragma unroll
        for (int m = 0; m < 4; m++)
            #pragma unroll
            for (int n = 0; n < 4; n++)
                acc[m][n] = __builtin_amdgcn_mfma_f32_16x16x32_bf16(av[m], bv[n],
                                                                    acc[m][n], 0, 0, 0);
        __syncthreads();
    }
    #pragma unroll
    for (int m = 0; m < 4; m++) {
        #pragma unroll
        for (int j = 0; j < 4; j++) {
            long r = row0 + wr * 64 + m * 16 + quad * 4 + j;
            if (r < NNODES) {
                u16* op = out + r * HC + col0 + wc * 64 + l15;
                #pragma unroll
                for (int n = 0; n < 4; n++) op[n * 16] = f2b(acc[m][n][j]);
            }
        }
    }
}

// ---------------- a_s/a_d projection body, vectorized uint2 loads ----------------
template <int K, bool BN>
__device__ __forceinline__ void proj_body(const u16* __restrict__ X,
                                          const float* __restrict__ coef,
                                          const float* __restrict__ us,
                                          const float* __restrict__ ud,
                                          float* __restrict__ as_, float* __restrict__ ad_,
                                          int pb) {
    int gw = (pb * 256 + (int)threadIdx.x) >> 6;
    int lane = threadIdx.x & 63;
    int node, f0;
    if (K == 64) {
        node = gw * 4 + (lane >> 4);
        f0 = (lane & 15) * 4;
    } else {
        node = gw;
        f0 = lane * 4;
    }
    if (node >= NNODES) return;
    uint2 v = *(const uint2*)(X + (long)node * K + f0);
    float xv[4] = {b2f((u16)(v.x & 0xffffu)), b2f((u16)(v.x >> 16)),
                   b2f((u16)(v.y & 0xffffu)), b2f((u16)(v.y >> 16))};
    float pas[4] = {0.f, 0.f, 0.f, 0.f}, pad[4] = {0.f, 0.f, 0.f, 0.f};
    #pragma unroll
    for (int j = 0; j < 4; j++) {
        int f = f0 + j;
        float x = xv[j];
        if (BN) x = fmaxf(x * coef[f] + coef[256 + f], 0.f);
        #pragma unroll
        for (int h = 0; h < 4; h++) {
            pas[h] += x * us[f * 4 + h];
            pad[h] += x * ud[f * 4 + h];
        }
    }
    const int omax = (K == 64) ? 8 : 32;
    #pragma unroll
    for (int h = 0; h < 4; h++) {
        for (int o = omax; o; o >>= 1) {
            pas[h] += __shfl_xor(pas[h], o);
            pad[h] += __shfl_xor(pad[h], o);
        }
    }
    bool wr = (K == 64) ? ((lane & 15) == 0) : (lane == 0);
    if (wr) {
        #pragma unroll
        for (int h = 0; h < 4; h++) {
            as_[node * 4 + h] = pas[h];
            ad_[node * 4 + h] = pad[h];
        }
    }
}

// ---------------- layer-1 mix: edge_stage (3125) + gemm64 (782) + proj64 (3125) --------
#define GT 782
#define EB 3125
#define PB64 3125

__global__ __launch_bounds__(256) void l1_mix(
    const void* __restrict__ eattr_raw, const int* __restrict__ flag,
    const int* __restrict__ esrc, const int* __restrict__ edst,
    const float* __restrict__ ve1, const float* __restrict__ ve2,
    int* __restrict__ cursor, uint4* __restrict__ rec,
    const u16* __restrict__ xb, const u16* __restrict__ WT1, u16* __restrict__ bufA,
    const float* __restrict__ us1, const float* __restrict__ ud1,
    float* __restrict__ as_, float* __restrict__ ad_) {
    int b = blockIdx.x;
    if (b < EB) {
        edge_body(eattr_raw, flag, esrc, edst, ve1, ve2, cursor, rec, b);
        return;
    }
    b -= EB;
    if (b < GT) {
        gemm_body<64, false>(xb, WT1, nullptr, bufA, b);
        return;
    }
    b -= GT;
    proj_body<64, false>(xb, nullptr, us1, ud1, as_, ad_, b);
}

// ---------------- layer-2 mix: gemm256+BN (782) + proj256+BN (12500) ----------------
__global__ __launch_bounds__(256) void l2_mix(
    const u16* __restrict__ h1, const u16* __restrict__ WT2,
    const float* __restrict__ coef, u16* __restrict__ bufA,
    const float* __restrict__ us2, const float* __restrict__ ud2,
    float* __restrict__ as_, float* __restrict__ ad_) {
    int b = blockIdx.x;
    if (b < GT) {
        gemm_body<256, true>(h1, WT2, coef, bufA, b);
        return;
    }
    b -= GT;
    proj_body<256, true>(h1, coef, us2, ud2, as_, ad_, b);
}

// ---------------- fused GAT attention, one wave per dst node ----------------
__global__ __launch_bounds__(256) void gat_fused(
    const u16* __restrict__ xs, const float* __restrict__ as_, const float* __restrict__ ad_,
    const uint4* __restrict__ rec, int layer,
    const int* __restrict__ off, const int* __restrict__ deg,
    const u16* __restrict__ bias, u16* __restrict__ out) {
    __shared__ int s_lds[4][64];
    __shared__ float w_lds[4][64][4];
    int wid = (blockIdx.x * 256 + threadIdx.x) >> 6;
    if (wid >= NNODES) return;
    int wave = threadIdx.x >> 6;
    int lane = threadIdx.x & 63;
    int d = wid;
    int st = off[d], dg = deg[d];
    int slot = lane >> 2, h = lane & 3;
    float adv = ad_[d * 4 + h];
    float m = -1e30f, s = 0.f, sae = 0.f;
    const uint4* rbase = rec + (long)st * 2 + layer;

    if (dg <= 64) {
        for (int i = slot; i < dg; i += 16) {
            uint4 r4 = rbase[(long)i * 2];
            int src = (int)r4.x;
            unsigned wsel = (h & 2) ? r4.z : r4.y;
            float aev = b2f((u16)((h & 1) ? (wsel >> 16) : (wsel & 0xffffu)));
            float t = as_[src * 4 + h] + adv + aev;
            float lg = (t > 0.f) ? t : 0.2f * t;
            if (h == 0) s_lds[wave][i] = src;
            w_lds[wave][i][h] = lg;
            sae += aev;
            float mn = fmaxf(m, lg);
            s = s * __expf(m - mn) + __expf(lg - mn);
            m = mn;
        }
        #pragma unroll
        for (int o = 4; o < 64; o <<= 1) {
            float mo = __shfl_xor(m, o), so = __shfl_xor(s, o), ao = __shfl_xor(sae, o);
            float mn = fmaxf(m, mo);
            s = s * __expf(m - mn) + so * __expf(mo - mn);
            m = mn;
            sae += ao;
        }
        float invs, wself;
        {
            float asv = as_[d * 4 + h];
            float l0 = asv + adv + sae / fmaxf((float)dg, 1.f);
            l0 = (l0 > 0.f) ? l0 : 0.2f * l0;
            float mn = fmaxf(m, l0);
            s = s * __expf(m - mn) + __expf(l0 - mn);
            m = mn;
            invs = 1.f / s;
            wself = __expf(l0 - mn) * invs;
        }
        for (int i = slot; i < dg; i += 16)
            w_lds[wave][i][h] = __expf(w_lds[wave][i][h] - m) * invs;

        int cg = lane & 31, half = lane >> 5;
        int ch8 = cg * 8;
        int h2 = cg >> 3;
        float ws2 = __shfl(wself, h2);
        const u16* xbase = xs + ch8;
        float a0, a1, a2, a3, a4, a5, a6, a7;
        {
            uint4 v = *(const uint4*)(xbase + (long)d * HC);
            float wsf = half ? 0.f : ws2;
            a0 = wsf * b2f((u16)(v.x & 0xffffu)); a1 = wsf * b2f((u16)(v.x >> 16));
            a2 = wsf * b2f((u16)(v.y & 0xffffu)); a3 = wsf * b2f((u16)(v.y >> 16));
            a4 = wsf * b2f((u16)(v.z & 0xffffu)); a5 = wsf * b2f((u16)(v.z >> 16));
            a6 = wsf * b2f((u16)(v.w & 0xffffu)); a7 = wsf * b2f((u16)(v.w >> 16));
        }
        int i = half;
        for (; i + 6 < dg; i += 8) {
            float wA = w_lds[wave][i][h2];     int sA = s_lds[wave][i];
            float wB = w_lds[wave][i + 2][h2]; int sB = s_lds[wave][i + 2];
            float wC = w_lds[wave][i + 4][h2]; int sC = s_lds[wave][i + 4];
            float wD = w_lds[wave][i + 6][h2]; int sD = s_lds[wave][i + 6];
            uint4 vA = *(const uint4*)(xbase + (long)sA * HC);
            uint4 vB = *(const uint4*)(xbase + (long)sB * HC);
            uint4 vC = *(const uint4*)(xbase + (long)sC * HC);
            uint4 vD = *(const uint4*)(xbase + (long)sD * HC);
            a0 += wA * b2f((u16)(vA.x & 0xffffu)) + wB * b2f((u16)(vB.x & 0xffffu))
                + wC * b2f((u16)(vC.x & 0xffffu)) + wD * b2f((u16)(vD.x & 0xffffu));
            a1 += wA * b2f((u16)(vA.x >> 16))     + wB * b2f((u16)(vB.x >> 16))
                + wC * b2f((u16)(vC.x >> 16))     + wD * b2f((u16)(vD.x >> 16));
            a2 += wA * b2f((u16)(vA.y & 0xffffu)) + wB * b2f((u16)(vB.y & 0xffffu))
                + wC * b2f((u16)(vC.y & 0xffffu)) + wD * b2f((u16)(vD.y & 0xffffu));
            a3 += wA * b2f((u16)(vA.y >> 16))     + wB * b2f((u16)(vB.y >> 16))
                + wC * b2f((u16)(vC.y >> 16))     + wD * b2f((u16)(vD.y >> 16));
            a4 += wA * b2f((u16)(vA.z & 0xffffu)) + wB * b2f((u16)(vB.z & 0xffffu))
                + wC * b2f((u16)(vC.z & 0xffffu)) + wD * b2f((u16)(vD.z & 0xffffu));
            a5 += wA * b2f((u16)(vA.z >> 16))     + wB * b2f((u16)(vB.z >> 16))
                + wC * b2f((u16)(vC.z >> 16))     + wD * b2f((u16)(vD.z >> 16));
            a6 += wA * b2f((u16)(vA.w & 0xffffu)) + wB * b2f((u16)(vB.w & 0xffffu))
                + wC * b2f((u16)(vC.w & 0xffffu)) + wD * b2f((u16)(vD.w & 0xffffu));
            a7 += wA * b2f((u16)(vA.w >> 16))     + wB * b2f((u16)(vB.w >> 16))
                + wC * b2f((u16)(vC.w >> 16))     + wD * b2f((u16)(vD.w >> 16));
        }
        for (; i < dg; i += 2) {
            float wA = w_lds[wave][i][h2]; int sA = s_lds[wave][i];
            uint4 vA = *(const uint4*)(xbase + (long)sA * HC);
            a0 += wA * b2f((u16)(vA.x & 0xffffu)); a1 += wA * b2f((u16)(vA.x >> 16));
            a2 += wA * b2f((u16)(vA.y & 0xffffu)); a3 += wA * b2f((u16)(vA.y >> 16));
            a4 += wA * b2f((u16)(vA.z & 0xffffu)); a5 += wA * b2f((u16)(vA.z >> 16));
            a6 += wA * b2f((u16)(vA.w & 0xffffu)); a7 += wA * b2f((u16)(vA.w >> 16));
        }
        a0 += __shfl_xor(a0, 32); a1 += __shfl_xor(a1, 32);
        a2 += __shfl_xor(a2, 32); a3 += __shfl_xor(a3, 32);
        a4 += __shfl_xor(a4, 32); a5 += __shfl_xor(a5, 32);
        a6 += __shfl_xor(a6, 32); a7 += __shfl_xor(a7, 32);
        if (half == 0) {
            uint4 bv = *(const uint4*)(bias + ch8);
            a0 += b2f((u16)(bv.x & 0xffffu)); a1 += b2f((u16)(bv.x >> 16));
            a2 += b2f((u16)(bv.y & 0xffffu)); a3 += b2f((u16)(bv.y >> 16));
            a4 += b2f((u16)(bv.z & 0xffffu)); a5 += b2f((u16)(bv.z >> 16));
            a6 += b2f((u16)(bv.w & 0xffffu)); a7 += b2f((u16)(bv.w >> 16));
            uint4 ov;
            ov.x = (unsigned)f2b(a0) | ((unsigned)f2b(a1) << 16);
            ov.y = (unsigned)f2b(a2) | ((unsigned)f2b(a3) << 16);
            ov.z = (unsigned)f2b(a4) | ((unsigned)f2b(a5) << 16);
            ov.w = (unsigned)f2b(a6) | ((unsigned)f2b(a7) << 16);
            *(uint4*)(out + (long)d * HC + ch8) = ov;
        }
        return;
    }

    // ---------- fallback path (deg > 64): exact ----------
    for (int base = 0; base < dg; base += 16) {
        int i = base + slot;
        float lg = -1e30f, aev = 0.f, w = 0.f;
        if (i < dg) {
            uint4 r4 = rbase[(long)i * 2];
            int src = (int)r4.x;
            unsigned wsel = (h & 2) ? r4.z : r4.y;
            aev = b2f((u16)((h & 1) ? (wsel >> 16) : (wsel & 0xffffu)));
            float t = as_[src * 4 + h] + adv + aev;
            lg = (t > 0.f) ? t : 0.2f * t;
        }
        sae += aev;
        float mn = fmaxf(m, lg);
        if (i < dg) w = __expf(lg - mn);
        s = s * __expf(m - mn) + w;
        m = mn;
    }
    #pragma unroll
    for (int o = 4; o < 64; o <<= 1) {
        float mo = __shfl_xor(m, o), so = __shfl_xor(s, o), ao = __shfl_xor(sae, o);
        float mn = fmaxf(m, mo);
        s = s * __expf(m - mn) + so * __expf(mo - mn);
        m = mn;
        sae += ao;
    }
    float invs, wself;
    {
        float asv = as_[d * 4 + h];
        float l0 = asv + adv + sae / fmaxf((float)dg, 1.f);
        l0 = (l0 > 0.f) ? l0 : 0.2f * l0;
        float mn = fmaxf(m, l0);
        s = s * __expf(m - mn) + __expf(l0 - mn);
        m = mn;
        invs = 1.f / s;
        wself = __expf(l0 - mn) * invs;
    }
    int h2 = lane >> 4;
    float m2 = __shfl(m, h2);
    float is2 = __shfl(invs, h2);
    float ws2 = __shfl(wself, h2);
    float adv2 = __shfl(adv, h2);
    int cb = lane * 4;
    float a0, a1, a2, a3;
    {
        uint2 v = *(const uint2*)(xs + (long)d * HC + cb);
        a0 = ws2 * b2f((u16)(v.x & 0xffffu)); a1 = ws2 * b2f((u16)(v.x >> 16));
        a2 = ws2 * b2f((u16)(v.y & 0xffffu)); a3 = ws2 * b2f((u16)(v.y >> 16));
    }
    int slot16 = lane & 15;
    int lhi = lane & 48;
    for (int base = 0; base < dg; base += 16) {
        int cnt = min(16, dg - base);
        float wv = 0.f;
        int srcl = 0;
        if (slot16 < cnt) {
            uint4 r4 = rbase[(long)(base + slot16) * 2];
            srcl = (int)r4.x;
            unsigned wsel = (h2 & 2) ? r4.z : r4.y;
            float aev = b2f((u16)((h2 & 1) ? (wsel >> 16) : (wsel & 0xffffu)));
            float t = as_[srcl * 4 + h2] + adv2 + aev;
            t = (t > 0.f) ? t : 0.2f * t;
            wv = __expf(t - m2) * is2;
        }
        for (int j = 0; j < cnt; j++) {
            float w0 = __shfl(wv, lhi | j);
            int s0 = __shfl(srcl, j);
            uint2 v0 = *(const uint2*)(xs + (long)s0 * HC + cb);
            a0 += w0 * b2f((u16)(v0.x & 0xffffu));
            a1 += w0 * b2f((u16)(v0.x >> 16));
            a2 += w0 * b2f((u16)(v0.y & 0xffffu));
            a3 += w0 * b2f((u16)(v0.y >> 16));
        }
    }
    u16 o0 = f2b(a0 + b2f(bias[cb + 0]));
    u16 o1 = f2b(a1 + b2f(bias[cb + 1]));
    u16 o2 = f2b(a2 + b2f(bias[cb + 2]));
    u16 o3 = f2b(a3 + b2f(bias[cb + 3]));
    uint2 ov;
    ov.x = (unsigned)o0 | ((unsigned)o1 << 16);
    ov.y = (unsigned)o2 | ((unsigned)o3 << 16);
    *(uint2*)(out + (long)d * HC + cb) = ov;
}

// ---------------- BatchNorm stats (4-row ILP, 512 blocks) + last-block coef finalize ----
__global__ __launch_bounds__(256) void bn_stats(const u16* __restrict__ h,
                                                float* __restrict__ stats,
                                                int* __restrict__ cnt,
                                                const u16* __restrict__ g,
                                                const u16* __restrict__ be,
                                                float* __restrict__ coef) {
    __shared__ float lsum[256], lsq[256];
    __shared__ int last;
    int t = threadIdx.x;
    int p = t & 127;   // column pair -> cols 2p, 2p+1
    int ro = t >> 7;   // 0: rows +0..3 of group, 1: rows +4..7
    float s0 = 0.f, q0 = 0.f, s1 = 0.f, q1 = 0.f;
    const u16* hp = h + 2 * p;
    for (long r = (long)blockIdx.x * 8 + ro * 4; r < NNODES; r += (long)gridDim.x * 8) {
        unsigned v0 = *(const unsigned*)(hp + (r + 0) * HC);
        unsigned v1 = *(const unsigned*)(hp + (r + 1) * HC);
        unsigned v2 = *(const unsigned*)(hp + (r + 2) * HC);
        unsigned v3 = *(const unsigned*)(hp + (r + 3) * HC);
        float l0 = b2f((u16)(v0 & 0xffffu)), h0 = b2f((u16)(v0 >> 16));
        float l1 = b2f((u16)(v1 & 0xffffu)), h1 = b2f((u16)(v1 >> 16));
        float l2 = b2f((u16)(v2 & 0xffffu)), h2 = b2f((u16)(v2 >> 16));
        float l3 = b2f((u16)(v3 & 0xffffu)), h3 = b2f((u16)(v3 >> 16));
        s0 += l0 + l1 + l2 + l3;
        q0 += l0 * l0 + l1 * l1 + l2 * l2 + l3 * l3;
        s1 += h0 + h1 + h2 + h3;
        q1 += h0 * h0 + h1 * h1 + h2 * h2 + h3 * h3;
    }
    if (ro == 1) {
        lsum[2 * p] = s0; lsum[2 * p + 1] = s1;
        lsq[2 * p] = q0;  lsq[2 * p + 1] = q1;
    }
    __syncthreads();
    if (ro == 0) {
        atomicAdd(&stats[2 * p],           s0 + lsum[2 * p]);
        atomicAdd(&stats[2 * p + 1],       s1 + lsum[2 * p + 1]);
        atomicAdd(&stats[256 + 2 * p],     q0 + lsq[2 * p]);
        atomicAdd(&stats[256 + 2 * p + 1], q1 + lsq[2 * p + 1]);
    }
    // last-block finalize (replaces bn_coef dispatch)
    __threadfence();
    __syncthreads();
    if (t == 0) {
        int old = atomicAdd(cnt, 1);
        last = (old == (int)gridDim.x - 1);
    }
    __syncthreads();
    if (last) {
        float sum = atomicAdd(&stats[t], 0.f);       // atomic read: L2-coherent
        float sq  = atomicAdd(&stats[256 + t], 0.f);
        float mu = sum * (1.0f / NNODES);
        float var = sq * (1.0f / NNODES) - mu * mu;
        var = fmaxf(var, 0.f);
        float rs = rsqrtf(var + 1e-5f);
        float sc = b2f(g[t]) * rs;
        coef[t] = sc;
        coef[256 + t] = b2f(be[t]) - sc * mu;
    }
}

// ---------------- output head (+fused BN2+ReLU), vectorized ----------------
__global__ __launch_bounds__(256) void out_head(const u16* __restrict__ h,
                                                const float* __restrict__ coef,
                                                const u16* __restrict__ wout,
                                                const u16* __restrict__ bout,
                                                void* __restrict__ y,
                                                const int* __restrict__ flag) {
    int wid = (blockIdx.x * 256 + threadIdx.x) >> 6;
    int lane = threadIdx.x & 63;
    if (wid >= NNODES) return;
    int c0 = lane * 4;
    uint2 v = *(const uint2*)(h + (long)wid * HC + c0);
    uint2 wv = *(const uint2*)(wout + c0);
    float hv[4] = {b2f((u16)(v.x & 0xffffu)), b2f((u16)(v.x >> 16)),
                   b2f((u16)(v.y & 0xffffu)), b2f((u16)(v.y >> 16))};
    float wf[4] = {b2f((u16)(wv.x & 0xffffu)), b2f((u16)(wv.x >> 16)),
                   b2f((u16)(wv.y & 0xffffu)), b2f((u16)(wv.y >> 16))};
    float p = 0.f;
    #pragma unroll
    for (int j = 0; j < 4; j++) {
        float t = fmaxf(hv[j] * coef[c0 + j] + coef[256 + c0 + j], 0.f);
        p += t * wf[j];
    }
    for (int o = 32; o; o >>= 1) p += __shfl_down(p, o);
    if (lane == 0) {
        float t = p + b2f(bout[0]);
        if (*flag) ((u16*)y)[wid] = f2b(t);
        else       ((float*)y)[wid] = t;
    }
}

extern "C" void kernel_launch(void* const* d_in, const int* in_sizes, int n_in,
                              void* d_out, int out_size, void* d_ws, size_t ws_size,
                              hipStream_t stream) {
    (void)in_sizes; (void)n_in; (void)out_size; (void)ws_size;
    const void* x_raw     = d_in[0];
    const int*  esrc      = (const int*)d_in[1];
    const int*  edst      = (const int*)d_in[2];
    const void* eattr_raw = d_in[3];

    char* ws = (char*)d_ws;
    size_t o = 0;
    auto alloc = [&](size_t bytes) -> char* {
        o = (o + 255) & ~(size_t)255;
        char* p = ws + o;
        o += bytes;
        return p;
    };
    int* dflag = (int*)alloc(256);
    u16* xb   = (u16*)alloc((size_t)NNODES * 64 * 2);
    u16* pall = (u16*)alloc((size_t)TOTP * 2);
    u16 *b1b = pall + hPO[5], *g1b = pall + hPO[6], *be1b = pall + hPO[7],
        *b2b = pall + hPO[13], *g2b = pall + hPO[14], *be2b = pall + hPO[15],
        *Woutb = pall + hPO[16], *boutb = pall + hPO[17];
    u16* WT1 = (u16*)alloc(256 * 64 * 2);
    u16* WT2 = (u16*)alloc(256 * 256 * 2);
    float* ve1 = (float*)alloc(64 * 4);
    float* ve2 = (float*)alloc(64 * 4);
    float* us1 = (float*)alloc(256 * 4);
    float* ud1 = (float*)alloc(256 * 4);
    float* us2 = (float*)alloc(1024 * 4);
    float* ud2 = (float*)alloc(1024 * 4);
    float* coef1 = (float*)alloc(512 * 4);
    float* coef2 = (float*)alloc(512 * 4);
    // zero zone: deg + stats + bn counters
    int* deg = (int*)alloc((size_t)NNODES * 4);
    float* stats1 = (float*)alloc(512 * 4);
    float* stats2 = (float*)alloc(512 * 4);
    int* bnc1 = (int*)alloc(256);
    int* bnc2 = (int*)alloc(256);
    size_t zero_end = o;
    size_t zero_begin = (size_t)((char*)deg - ws);
    // rest
    int* off = (int*)alloc((size_t)NNODES * 4);
    int* cursor = (int*)alloc((size_t)NNODES * 4);
    int* bsums = (int*)alloc(256 * 4);
    uint4* rec = (uint4*)alloc((size_t)NEDGES * 32);
    float* as_ = (float*)alloc((size_t)NNODES * 16);
    float* ad_ = (float*)alloc((size_t)NNODES * 16);
    u16* bufA = (u16*)alloc((size_t)NNODES * HC * 2);  // xs1, then xs2
    u16* bufB = (u16*)alloc((size_t)NNODES * HC * 2);  // h1raw, then h2raw

    long zwords = (long)((zero_end - zero_begin) / 4);
    prep0<<<129, 256, 0, stream>>>((unsigned*)(ws + zero_begin), zwords,
                                   (const unsigned*)x_raw, dflag);

    Ptrs18 pp;
    for (int i = 0; i < 18; i++) pp.s[i] = d_in[4 + i];
    param_prep<<<NB_PREP, 256, 0, stream>>>(pp, x_raw, edst, dflag, xb, pall, WT1, WT2,
                                            ve1, ve2, us1, ud1, us2, ud2, deg);

    int nb = (NNODES + 255) / 256;  // 196
    block_sum<<<nb, 256, 0, stream>>>(deg, bsums, NNODES);
    scan_write<<<nb, 256, 0, stream>>>(bsums, deg, off, cursor, NNODES, nb);

    int wblocks = (NNODES * 64 + 255) / 256;  // 12500 (1 wave per node)

    // layer 1: edge_stage + gemm64 + proj64 in one MPMD dispatch
    l1_mix<<<EB + GT + PB64, 256, 0, stream>>>(eattr_raw, dflag, esrc, edst, ve1, ve2,
                                               cursor, rec, xb, WT1, bufA,
                                               us1, ud1, as_, ad_);
    gat_fused<<<wblocks, 256, 0, stream>>>(bufA, as_, ad_, rec, 0, off, deg, b1b, bufB);
    bn_stats<<<512, 256, 0, stream>>>(bufB, stats1, bnc1, g1b, be1b, coef1);

    // layer 2: gemm256+BN + proj256+BN in one MPMD dispatch
    l2_mix<<<GT + wblocks, 256, 0, stream>>>(bufB, WT2, coef1, bufA, us2, ud2, as_, ad_);
    gat_fused<<<wblocks, 256, 0, stream>>>(bufA, as_, ad_, rec, 1, off, deg, b2b, bufB);
    bn_stats<<<512, 256, 0, stream>>>(bufB, stats2, bnc2, g2b, be2b, coef2);

    // output head (BN2 fused)
    out_head<<<wblocks, 256, 0, stream>>>(bufB, coef2, Woutb, boutb, d_out, dflag);
}